// Round 10
// baseline (802.583 us; speedup 1.0000x reference)
//
#include <hip/hip_runtime.h>
#include <hip/hip_bf16.h>

// Problem: VectorQuantizer. z: [32,256,32,32] f32 NCHW, codebook: [1024,256] f32.
// Outputs (concat f32): z_q_out [32,256,32,32], loss[1], perplexity[1], idx[32768] (as float), mean_distance[1].
// idx must replicate numpy-fp32 argmin of d = fl32(fl32(s_n + t_k) - 2*fl32(dot)).
// Screen: split-bf16 MFMA, 2 products (zh.eh + zh.el), no LDS; exact-np recheck for near-ties.

#define NPTS   32768
#define KCODE  1024
#define DDIM   256
#define HWSZ   1024
#define ZSTRB  262144
#define ZELEMS 8388608

#define OUT_LOSS 8388608
#define OUT_PERP 8388609
#define OUT_IDX  8388610
#define OUT_MD   8421378

// ws byte offsets
#define WS_IDX     0        // int[32768]
#define WS_COUNTS  131072   // int[1024]
#define WS_RLIST   135168   // int[32768]
#define WS_RCOUNT  266240   // int
#define WS_LOSSSUM 266248   // double
#define WS_ZSQ     266256   // double
#define WS_ENSUM   266264   // double
#define WS_CHSUM   266272   // double[256]
#define WS_ESUM    268320   // double[256]
#define WS_ENORM   270368   // float[1024]
#define WS_CBT     274464   // float[256*1024]
#define WS_CBHI    1323040  // ushort[1024*256] bf16 hi
#define WS_CBLO    1847328  // ushort[1024*256] bf16 lo

// screen err (2-product split-bf16): pairwise ~3e-5 std; np flip window 6.2e-5; ~8 sigma headroom
#define MARGIN 3e-4f

typedef short  s16x8 __attribute__((ext_vector_type(8)));
typedef unsigned short u16x8 __attribute__((ext_vector_type(8)));
typedef float  f32x4 __attribute__((ext_vector_type(4)));

__device__ __forceinline__ unsigned short bf16_rne(float f) {
    unsigned int u = __float_as_uint(f);
    return (unsigned short)((u + 0x7FFFu + ((u >> 16) & 1u)) >> 16);
}

__global__ __launch_bounds__(256) void init_kernel(char* ws) {
    int t = threadIdx.x;
    int* counts = (int*)(ws + WS_COUNTS);
    for (int i = t; i < 1024; i += 256) counts[i] = 0;
    if (t == 0) *(int*)(ws + WS_RCOUNT) = 0;
    double* dbl = (double*)(ws + WS_LOSSSUM);
    for (int i = t; i < 515; i += 256) dbl[i] = 0.0;
}

// numpy pairwise fp32 sum of squares of a 256-row (exact tree; asm stops FMA contraction)
__device__ __forceinline__ float np_sumsq256(const float* p) {
    float tot[2];
    #pragma unroll
    for (int h = 0; h < 2; ++h) {
        const float* a = p + h * 128;
        float r[8];
        #pragma unroll
        for (int j = 0; j < 8; ++j) { float v = a[j]; float s = v * v; asm volatile("" : "+v"(s)); r[j] = s; }
        for (int i = 8; i < 128; i += 8) {
            #pragma unroll
            for (int j = 0; j < 8; ++j) { float v = a[i + j]; float s = v * v; asm volatile("" : "+v"(s)); r[j] += s; }
        }
        tot[h] = ((r[0] + r[1]) + (r[2] + r[3])) + ((r[4] + r[5]) + (r[6] + r[7]));
    }
    return tot[0] + tot[1];
}

// per 16 codes (64 blocks): np-fp32 enorm, cbT[d][k], cb hi/lo bf16, fp64 column sums + norm total
__global__ __launch_bounds__(256) void prep2_kernel(const float* __restrict__ cb,
                                                    float* __restrict__ enorm,
                                                    float* __restrict__ cbT,
                                                    unsigned short* __restrict__ cbhi,
                                                    unsigned short* __restrict__ cblo,
                                                    double* __restrict__ esum,
                                                    double* __restrict__ enormsum) {
    __shared__ float tile[16][257];
    int t = threadIdx.x;
    int k0 = blockIdx.x * 16;           // 64 blocks

    #pragma unroll
    for (int i = 0; i < 4; ++i) {
        int f = t + 256 * i;            // float4 index
        int r = f >> 6;
        int c4 = (f & 63) << 2;
        float4 v = *(const float4*)(cb + (size_t)(k0 + r) * DDIM + c4);
        tile[r][c4] = v.x; tile[r][c4 + 1] = v.y; tile[r][c4 + 2] = v.z; tile[r][c4 + 3] = v.w;
    }
    __syncthreads();

    if (t < 16) {
        float s = np_sumsq256(&tile[t][0]);
        enorm[k0 + t] = s;
        double en = (double)s;
        for (int o = 8; o; o >>= 1) en += __shfl_down(en, o, 64);
        if (t == 0) atomicAdd(enormsum, en);
    }

    double cs = 0.0;
    for (int r = 0; r < 16; ++r) cs += (double)tile[r][t];
    atomicAdd(&esum[t], cs);

    // cbT transposed write for recheck: 16-lane groups write 16 consecutive k
    {
        int kloc = t & 15, dg = t >> 4;
        #pragma unroll
        for (int dd = 0; dd < 16; ++dd) {
            int d = dd * 16 + dg;
            cbT[(size_t)d * KCODE + k0 + kloc] = tile[kloc][d];
        }
    }

    // split-bf16 hi/lo rows (row-major [k][d]); thread handles row t>>4, dims (t&15)*16..+16
    {
        int row = t >> 4;
        int d0 = (t & 15) * 16;
        #pragma unroll
        for (int j = 0; j < 2; ++j) {
            u16x8 H, L;
            #pragma unroll
            for (int e = 0; e < 8; ++e) {
                float f = tile[row][d0 + j * 8 + e];
                unsigned short h = bf16_rne(f);
                H[e] = h;
                L[e] = bf16_rne(f - __uint_as_float((unsigned int)h << 16));
            }
            *(u16x8*)(cbhi + (size_t)(k0 + row) * DDIM + d0 + j * 8) = H;
            *(u16x8*)(cblo + (size_t)(k0 + row) * DDIM + d0 + j * 8) = L;
        }
    }
}

// MFMA screen v2: no LDS. 64 points/block (4 waves x 16-point tiles), all 1024 codes/wave.
// Each lane builds its A-fragments (zh bf16) straight from global z; B streams hi/lo from L2.
// dot ~= zh.eh + zh.el (2 fp32 MFMA chains); criterion -> best/sec/idx; butterfly merge.
__global__ __launch_bounds__(256, 4) void screen_kernel(const float* __restrict__ z,
                                                        const unsigned short* __restrict__ cbhi,
                                                        const unsigned short* __restrict__ cblo,
                                                        const float* __restrict__ enorm,
                                                        int* __restrict__ ws_idx,
                                                        int* __restrict__ rlist,
                                                        int* __restrict__ rcount) {
    int tid = threadIdx.x;
    int n0 = blockIdx.x * 64;
    int b = n0 >> 10, hw0 = n0 & 1023;
    int lane = tid & 63;
    int w = tid >> 6;
    int col = lane & 15;        // A-row (point slot) and B-col (code slot)
    int kq = lane >> 4;         // K-quarter

    // A-fragments direct from global: point hw0 + w*16 + col, dims kc*32 + kq*8 + e
    const float* zp = z + (size_t)b * ZSTRB + (hw0 + w * 16 + col);
    s16x8 ah[8];
    #pragma unroll
    for (int kc = 0; kc < 8; ++kc) {
        u16x8 H;
        #pragma unroll
        for (int e = 0; e < 8; ++e)
            H[e] = bf16_rne(zp[(size_t)(kc * 32 + kq * 8 + e) << 10]);
        union { u16x8 u; s16x8 s; } cvt; cvt.u = H;
        ah[kc] = cvt.s;
    }

    float best[4] = {3.4e38f, 3.4e38f, 3.4e38f, 3.4e38f};
    float sec[4]  = {3.4e38f, 3.4e38f, 3.4e38f, 3.4e38f};
    int bidx[4] = {0, 0, 0, 0};

    const char* bhbase = (const char*)cbhi + col * 512 + kq * 16;
    const char* blbase = (const char*)cblo + col * 512 + kq * 16;

    #pragma unroll 1
    for (int chunk = 0; chunk < 64; ++chunk) {
        const char* bh = bhbase + chunk * 8192;
        const char* bl = blbase + chunk * 8192;
        f32x4 hh = {0.f, 0.f, 0.f, 0.f};
        f32x4 hl = {0.f, 0.f, 0.f, 0.f};
        #pragma unroll
        for (int kc = 0; kc < 8; ++kc) {
            s16x8 vbh = *(const s16x8*)(bh + kc * 64);
            s16x8 vbl = *(const s16x8*)(bl + kc * 64);
            hh = __builtin_amdgcn_mfma_f32_16x16x32_bf16(ah[kc], vbh, hh, 0, 0, 0);
            hl = __builtin_amdgcn_mfma_f32_16x16x32_bf16(ah[kc], vbl, hl, 0, 0, 0);
        }
        int k = chunk * 16 + col;
        float ek = enorm[k];
        #pragma unroll
        for (int r = 0; r < 4; ++r) {
            float dot = hh[r] + hl[r];
            float c = fmaf(-2.f, dot, ek);
            if (c < best[r]) { sec[r] = best[r]; best[r] = c; bidx[r] = k; }
            else if (c < sec[r]) sec[r] = c;
        }
    }

    // merge across 16 code-columns; ties -> lower idx; equal values leave sec==best -> flagged
    #pragma unroll
    for (int m = 1; m < 16; m <<= 1) {
        #pragma unroll
        for (int r = 0; r < 4; ++r) {
            float ob = __shfl_xor(best[r], m, 64);
            float os = __shfl_xor(sec[r], m, 64);
            int   oi = __shfl_xor(bidx[r], m, 64);
            if (ob < best[r] || (ob == best[r] && oi < bidx[r])) {
                sec[r] = fminf(best[r], os);
                best[r] = ob; bidx[r] = oi;
            } else {
                sec[r] = fminf(sec[r], ob);
            }
        }
    }

    if (col == 0) {
        #pragma unroll
        for (int r = 0; r < 4; ++r) {
            int n = n0 + w * 16 + kq * 4 + r;   // C row = kq*4 + r
            ws_idx[n] = bidx[r];
            if (sec[r] - best[r] < MARGIN) {
                int slot = atomicAdd(rcount, 1);
                if (slot < NPTS) rlist[slot] = n;
            }
        }
    }
}

// Recheck flagged points replicating numpy fp32 semantics; fp64 dot with 4-way ILP.
__global__ __launch_bounds__(256) void recheck_kernel(const float* __restrict__ z,
                                                      const float* __restrict__ cbT,
                                                      const float* __restrict__ enorm,
                                                      int* __restrict__ ws_idx,
                                                      const int* __restrict__ rlist,
                                                      const int* __restrict__ rcount) {
    __shared__ float zs[DDIM];
    __shared__ float s_sh;
    __shared__ float bv[256];
    __shared__ int   bi[256];
    int t = threadIdx.x;
    int cnt = *rcount; if (cnt > NPTS) cnt = NPTS;
    for (int it = blockIdx.x; it < cnt; it += gridDim.x) {
        int n = rlist[it];
        int b = n >> 10, hw = n & 1023;
        zs[t] = z[(size_t)b * ZSTRB + (size_t)t * HWSZ + hw];
        __syncthreads();
        if (t == 0) s_sh = np_sumsq256(zs);
        __syncthreads();
        float s_n = s_sh;
        float best = 3.4e38f; int bidx = 0;
        #pragma unroll
        for (int j = 0; j < 4; ++j) {
            int k = t + 256 * j;
            double a0 = 0.0, a1 = 0.0, a2 = 0.0, a3 = 0.0;
            for (int d = 0; d < DDIM; d += 4) {
                a0 = fma((double)cbT[(d + 0) * KCODE + k], (double)zs[d + 0], a0);
                a1 = fma((double)cbT[(d + 1) * KCODE + k], (double)zs[d + 1], a1);
                a2 = fma((double)cbT[(d + 2) * KCODE + k], (double)zs[d + 2], a2);
                a3 = fma((double)cbT[(d + 3) * KCODE + k], (double)zs[d + 3], a3);
            }
            double dot = (a0 + a1) + (a2 + a3);
            float E = (float)dot;
            float w = 2.0f * E;
            float u = s_n + enorm[k];
            float dd = u - w;
            if (dd < best) { best = dd; bidx = k; }
        }
        bv[t] = best; bi[t] = bidx;
        __syncthreads();
        for (int s2 = 128; s2; s2 >>= 1) {
            if (t < s2) {
                if (bv[t + s2] < bv[t] || (bv[t + s2] == bv[t] && bi[t + s2] < bi[t])) {
                    bv[t] = bv[t + s2]; bi[t] = bi[t + s2];
                }
            }
            __syncthreads();
        }
        if (t == 0) ws_idx[n] = bi[0];
        __syncthreads();
    }
}

__global__ __launch_bounds__(256) void hist_kernel(const int* __restrict__ ws_idx,
                                                   int* __restrict__ counts,
                                                   float* __restrict__ out_idx) {
    __shared__ int h[KCODE];
    int t = threadIdx.x;
    for (int i = t; i < KCODE; i += 256) h[i] = 0;
    __syncthreads();
    int n = blockIdx.x * 256 + t;
    int idx = ws_idx[n];
    out_idx[n] = (float)idx;
    atomicAdd(&h[idx], 1);
    __syncthreads();
    for (int i = t; i < KCODE; i += 256) { int c = h[i]; if (c) atomicAdd(&counts[i], c); }
}

__global__ __launch_bounds__(256) void out_kernel(const float* __restrict__ z,
                                                  const float* __restrict__ cb,
                                                  const int* __restrict__ ws_idx,
                                                  float* __restrict__ out,
                                                  double* __restrict__ lossSum,
                                                  double* __restrict__ chsum,
                                                  double* __restrict__ zsq) {
    int t = threadIdx.x;
    size_t base = (size_t)blockIdx.x * 1024;
    int c = blockIdx.x & 255;
    int b = blockIdx.x >> 8;
    int hw = t * 4;
    const float4 zv = *(const float4*)(z + base + hw);
    int4 iv = *(const int4*)(ws_idx + b * HWSZ + hw);
    float q0 = cb[(size_t)iv.x * DDIM + c];
    float q1 = cb[(size_t)iv.y * DDIM + c];
    float q2 = cb[(size_t)iv.z * DDIM + c];
    float q3 = cb[(size_t)iv.w * DDIM + c];
    float t0 = q0 - zv.x, t1 = q1 - zv.y, t2 = q2 - zv.z, t3 = q3 - zv.w;
    float4 o; o.x = zv.x + t0; o.y = zv.y + t1; o.z = zv.z + t2; o.w = zv.w + t3;
    *(float4*)(out + base + hw) = o;

    double ls  = (double)t0 * t0 + (double)t1 * t1 + (double)t2 * t2 + (double)t3 * t3;
    double zs  = (double)zv.x + (double)zv.y + (double)zv.z + (double)zv.w;
    double zq2 = (double)zv.x * zv.x + (double)zv.y * zv.y + (double)zv.z * zv.z + (double)zv.w * zv.w;

    __shared__ double r1[4], r2[4], r3[4];
    for (int o2 = 32; o2; o2 >>= 1) {
        ls  += __shfl_down(ls,  o2, 64);
        zs  += __shfl_down(zs,  o2, 64);
        zq2 += __shfl_down(zq2, o2, 64);
    }
    if ((t & 63) == 0) { int w = t >> 6; r1[w] = ls; r2[w] = zs; r3[w] = zq2; }
    __syncthreads();
    if (t == 0) {
        atomicAdd(lossSum, r1[0] + r1[1] + r1[2] + r1[3]);
        atomicAdd(&chsum[c], r2[0] + r2[1] + r2[2] + r2[3]);
        atomicAdd(zsq, r3[0] + r3[1] + r3[2] + r3[3]);
    }
}

__global__ __launch_bounds__(256) void fin_kernel(const int* __restrict__ counts,
                                                  const double* __restrict__ lossSum,
                                                  const double* __restrict__ chsum,
                                                  const double* __restrict__ esum,
                                                  const double* __restrict__ zsq,
                                                  const double* __restrict__ enormsum,
                                                  float* __restrict__ out) {
    int t = threadIdx.x;
    double ent = 0.0;
    for (int i = t; i < KCODE; i += 256) {
        float em = (float)counts[i] / 32768.0f;
        ent += (double)(em * logf(em + 1e-10f));
    }
    double pd = chsum[t] * esum[t];

    __shared__ double r1[4], r2[4];
    for (int o2 = 32; o2; o2 >>= 1) {
        ent += __shfl_down(ent, o2, 64);
        pd  += __shfl_down(pd,  o2, 64);
    }
    if ((t & 63) == 0) { int w = t >> 6; r1[w] = ent; r2[w] = pd; }
    __syncthreads();
    if (t == 0) {
        double ENT = r1[0] + r1[1] + r1[2] + r1[3];
        double PD  = r2[0] + r2[1] + r2[2] + r2[3];
        float m = (float)(*lossSum / (double)ZELEMS);
        out[OUT_LOSS] = 0.25f * m + m;
        out[OUT_PERP] = expf((float)(-ENT));
        double md = *zsq / (double)NPTS + *enormsum / (double)KCODE
                    - (2.0 / ((double)NPTS * (double)KCODE)) * PD;
        out[OUT_MD] = (float)md;
    }
}

extern "C" void kernel_launch(void* const* d_in, const int* in_sizes, int n_in,
                              void* d_out, int out_size, void* d_ws, size_t ws_size,
                              hipStream_t stream) {
    const float* z  = (const float*)d_in[0];
    const float* cb = (const float*)d_in[1];
    float* out = (float*)d_out;
    char* ws = (char*)d_ws;

    int*    ws_idx   = (int*)(ws + WS_IDX);
    int*    counts   = (int*)(ws + WS_COUNTS);
    int*    rlist    = (int*)(ws + WS_RLIST);
    int*    rcount   = (int*)(ws + WS_RCOUNT);
    double* lossSum  = (double*)(ws + WS_LOSSSUM);
    double* zsq      = (double*)(ws + WS_ZSQ);
    double* enormsum = (double*)(ws + WS_ENSUM);
    double* chsum    = (double*)(ws + WS_CHSUM);
    double* esum     = (double*)(ws + WS_ESUM);
    float*  enorm    = (float*)(ws + WS_ENORM);
    float*  cbT      = (float*)(ws + WS_CBT);
    unsigned short* cbhi = (unsigned short*)(ws + WS_CBHI);
    unsigned short* cblo = (unsigned short*)(ws + WS_CBLO);

    hipLaunchKernelGGL(init_kernel, dim3(1), dim3(256), 0, stream, ws);
    hipLaunchKernelGGL(prep2_kernel, dim3(64), dim3(256), 0, stream,
                       cb, enorm, cbT, cbhi, cblo, esum, enormsum);
    hipLaunchKernelGGL(screen_kernel, dim3(512), dim3(256), 0, stream,
                       z, cbhi, cblo, enorm, ws_idx, rlist, rcount);
    hipLaunchKernelGGL(recheck_kernel, dim3(512), dim3(256), 0, stream,
                       z, cbT, enorm, ws_idx, rlist, rcount);
    hipLaunchKernelGGL(hist_kernel, dim3(128), dim3(256), 0, stream,
                       ws_idx, counts, out + OUT_IDX);
    hipLaunchKernelGGL(out_kernel, dim3(8192), dim3(256), 0, stream,
                       z, cb, ws_idx, out, lossSum, chsum, zsq);
    hipLaunchKernelGGL(fin_kernel, dim3(1), dim3(256), 0, stream,
                       counts, lossSum, chsum, esum, zsq, enormsum, out);
}

// Round 11
// 731.084 us; speedup vs baseline: 1.0978x; 1.0978x over previous
//
#include <hip/hip_runtime.h>
#include <hip/hip_bf16.h>

// Problem: VectorQuantizer. z: [32,256,32,32] f32 NCHW, codebook: [1024,256] f32.
// Outputs (concat f32): z_q_out [32,256,32,32], loss[1], perplexity[1], idx[32768] (as float), mean_distance[1].
// idx must replicate numpy-fp32 argmin of d = fl32(fl32(s_n + t_k) - 2*fl32(dot)).
// Screen: split-bf16 MFMA, 2 products (zh.eh + zh.el), no LDS; batched exact-np recheck for near-ties.

#define NPTS   32768
#define KCODE  1024
#define DDIM   256
#define HWSZ   1024
#define ZSTRB  262144
#define ZELEMS 8388608

#define OUT_LOSS 8388608
#define OUT_PERP 8388609
#define OUT_IDX  8388610
#define OUT_MD   8421378

// ws byte offsets
#define WS_IDX     0        // int[32768]
#define WS_COUNTS  131072   // int[1024]
#define WS_RLIST   135168   // int[32768]
#define WS_RCOUNT  266240   // int
#define WS_LOSSSUM 266248   // double
#define WS_ZSQ     266256   // double
#define WS_ENSUM   266264   // double
#define WS_CHSUM   266272   // double[256]
#define WS_ESUM    268320   // double[256]
#define WS_ENORM   270368   // float[1024]
#define WS_CBT     274464   // float[256*1024]
#define WS_CBHI    1323040  // ushort[1024*256] bf16 hi
#define WS_CBLO    1847328  // ushort[1024*256] bf16 lo

// screen err (2-product split-bf16): pairwise ~2e-5 std; np flip window 6.2e-5
#define MARGIN 3e-4f

#define RTILE 8   // points per recheck tile

typedef short  s16x8 __attribute__((ext_vector_type(8)));
typedef unsigned short u16x8 __attribute__((ext_vector_type(8)));
typedef float  f32x4 __attribute__((ext_vector_type(4)));

__device__ __forceinline__ unsigned short bf16_rne(float f) {
    unsigned int u = __float_as_uint(f);
    return (unsigned short)((u + 0x7FFFu + ((u >> 16) & 1u)) >> 16);
}

__global__ __launch_bounds__(256) void init_kernel(char* ws) {
    int t = threadIdx.x;
    int* counts = (int*)(ws + WS_COUNTS);
    for (int i = t; i < 1024; i += 256) counts[i] = 0;
    if (t == 0) *(int*)(ws + WS_RCOUNT) = 0;
    double* dbl = (double*)(ws + WS_LOSSSUM);
    for (int i = t; i < 515; i += 256) dbl[i] = 0.0;
}

// numpy pairwise fp32 sum of squares of a 256-row (exact tree; asm stops FMA contraction)
__device__ __forceinline__ float np_sumsq256(const float* p) {
    float tot[2];
    #pragma unroll
    for (int h = 0; h < 2; ++h) {
        const float* a = p + h * 128;
        float r[8];
        #pragma unroll
        for (int j = 0; j < 8; ++j) { float v = a[j]; float s = v * v; asm volatile("" : "+v"(s)); r[j] = s; }
        for (int i = 8; i < 128; i += 8) {
            #pragma unroll
            for (int j = 0; j < 8; ++j) { float v = a[i + j]; float s = v * v; asm volatile("" : "+v"(s)); r[j] += s; }
        }
        tot[h] = ((r[0] + r[1]) + (r[2] + r[3])) + ((r[4] + r[5]) + (r[6] + r[7]));
    }
    return tot[0] + tot[1];
}

// per 16 codes (64 blocks): np-fp32 enorm, cbT[d][k], cb hi/lo bf16, fp64 column sums + norm total
__global__ __launch_bounds__(256) void prep2_kernel(const float* __restrict__ cb,
                                                    float* __restrict__ enorm,
                                                    float* __restrict__ cbT,
                                                    unsigned short* __restrict__ cbhi,
                                                    unsigned short* __restrict__ cblo,
                                                    double* __restrict__ esum,
                                                    double* __restrict__ enormsum) {
    __shared__ float tile[16][257];
    int t = threadIdx.x;
    int k0 = blockIdx.x * 16;           // 64 blocks

    #pragma unroll
    for (int i = 0; i < 4; ++i) {
        int f = t + 256 * i;            // float4 index
        int r = f >> 6;
        int c4 = (f & 63) << 2;
        float4 v = *(const float4*)(cb + (size_t)(k0 + r) * DDIM + c4);
        tile[r][c4] = v.x; tile[r][c4 + 1] = v.y; tile[r][c4 + 2] = v.z; tile[r][c4 + 3] = v.w;
    }
    __syncthreads();

    if (t < 16) {
        float s = np_sumsq256(&tile[t][0]);
        enorm[k0 + t] = s;
        double en = (double)s;
        for (int o = 8; o; o >>= 1) en += __shfl_down(en, o, 64);
        if (t == 0) atomicAdd(enormsum, en);
    }

    double cs = 0.0;
    for (int r = 0; r < 16; ++r) cs += (double)tile[r][t];
    atomicAdd(&esum[t], cs);

    // cbT transposed write for recheck
    {
        int kloc = t & 15, dg = t >> 4;
        #pragma unroll
        for (int dd = 0; dd < 16; ++dd) {
            int d = dd * 16 + dg;
            cbT[(size_t)d * KCODE + k0 + kloc] = tile[kloc][d];
        }
    }

    // split-bf16 hi/lo rows (row-major [k][d])
    {
        int row = t >> 4;
        int d0 = (t & 15) * 16;
        #pragma unroll
        for (int j = 0; j < 2; ++j) {
            u16x8 H, L;
            #pragma unroll
            for (int e = 0; e < 8; ++e) {
                float f = tile[row][d0 + j * 8 + e];
                unsigned short h = bf16_rne(f);
                H[e] = h;
                L[e] = bf16_rne(f - __uint_as_float((unsigned int)h << 16));
            }
            *(u16x8*)(cbhi + (size_t)(k0 + row) * DDIM + d0 + j * 8) = H;
            *(u16x8*)(cblo + (size_t)(k0 + row) * DDIM + d0 + j * 8) = L;
        }
    }
}

// MFMA screen: no LDS. 64 points/block (4 waves x 16-point tiles), all 1024 codes/wave.
__global__ __launch_bounds__(256, 4) void screen_kernel(const float* __restrict__ z,
                                                        const unsigned short* __restrict__ cbhi,
                                                        const unsigned short* __restrict__ cblo,
                                                        const float* __restrict__ enorm,
                                                        int* __restrict__ ws_idx,
                                                        int* __restrict__ rlist,
                                                        int* __restrict__ rcount) {
    int tid = threadIdx.x;
    int n0 = blockIdx.x * 64;
    int b = n0 >> 10, hw0 = n0 & 1023;
    int lane = tid & 63;
    int w = tid >> 6;
    int col = lane & 15;        // A-row (point slot) and B-col (code slot)
    int kq = lane >> 4;         // K-quarter

    const float* zp = z + (size_t)b * ZSTRB + (hw0 + w * 16 + col);
    s16x8 ah[8];
    #pragma unroll
    for (int kc = 0; kc < 8; ++kc) {
        u16x8 H;
        #pragma unroll
        for (int e = 0; e < 8; ++e)
            H[e] = bf16_rne(zp[(size_t)(kc * 32 + kq * 8 + e) << 10]);
        union { u16x8 u; s16x8 s; } cvt; cvt.u = H;
        ah[kc] = cvt.s;
    }

    float best[4] = {3.4e38f, 3.4e38f, 3.4e38f, 3.4e38f};
    float sec[4]  = {3.4e38f, 3.4e38f, 3.4e38f, 3.4e38f};
    int bidx[4] = {0, 0, 0, 0};

    const char* bhbase = (const char*)cbhi + col * 512 + kq * 16;
    const char* blbase = (const char*)cblo + col * 512 + kq * 16;

    #pragma unroll 1
    for (int chunk = 0; chunk < 64; ++chunk) {
        const char* bh = bhbase + chunk * 8192;
        const char* bl = blbase + chunk * 8192;
        f32x4 hh = {0.f, 0.f, 0.f, 0.f};
        f32x4 hl = {0.f, 0.f, 0.f, 0.f};
        #pragma unroll
        for (int kc = 0; kc < 8; ++kc) {
            s16x8 vbh = *(const s16x8*)(bh + kc * 64);
            s16x8 vbl = *(const s16x8*)(bl + kc * 64);
            hh = __builtin_amdgcn_mfma_f32_16x16x32_bf16(ah[kc], vbh, hh, 0, 0, 0);
            hl = __builtin_amdgcn_mfma_f32_16x16x32_bf16(ah[kc], vbl, hl, 0, 0, 0);
        }
        int k = chunk * 16 + col;
        float ek = enorm[k];
        #pragma unroll
        for (int r = 0; r < 4; ++r) {
            float dot = hh[r] + hl[r];
            float c = fmaf(-2.f, dot, ek);
            if (c < best[r]) { sec[r] = best[r]; best[r] = c; bidx[r] = k; }
            else if (c < sec[r]) sec[r] = c;
        }
    }

    #pragma unroll
    for (int m = 1; m < 16; m <<= 1) {
        #pragma unroll
        for (int r = 0; r < 4; ++r) {
            float ob = __shfl_xor(best[r], m, 64);
            float os = __shfl_xor(sec[r], m, 64);
            int   oi = __shfl_xor(bidx[r], m, 64);
            if (ob < best[r] || (ob == best[r] && oi < bidx[r])) {
                sec[r] = fminf(best[r], os);
                best[r] = ob; bidx[r] = oi;
            } else {
                sec[r] = fminf(sec[r], ob);
            }
        }
    }

    if (col == 0) {
        #pragma unroll
        for (int r = 0; r < 4; ++r) {
            int n = n0 + w * 16 + kq * 4 + r;
            ws_idx[n] = bidx[r];
            if (sec[r] - best[r] < MARGIN) {
                int slot = atomicAdd(rcount, 1);
                if (slot < NPTS) rlist[slot] = n;
            }
        }
    }
}

// Batched recheck: 8 flagged points per tile. Each thread: 4 codes x 8 points, fp64.
// Per d: 4 coalesced cbT loads (each reused 8x) + 8 LDS broadcasts + 32 FMAs.
// np-fp32 semantics: d(k) = fl32( fl32(s_n + t_k) - 2*fl32(dot64) ), first-index ties.
__global__ __launch_bounds__(256) void recheck_kernel(const float* __restrict__ z,
                                                      const float* __restrict__ cbT,
                                                      const float* __restrict__ enorm,
                                                      int* __restrict__ ws_idx,
                                                      const int* __restrict__ rlist,
                                                      const int* __restrict__ rcount) {
    __shared__ float zs[RTILE][DDIM + 1];   // pad breaks row-bank alignment
    __shared__ float s8[RTILE];
    __shared__ int   nn[RTILE];
    __shared__ float bv[256];
    __shared__ int   bi[256];
    int t = threadIdx.x;
    int cnt = *rcount; if (cnt > NPTS) cnt = NPTS;
    int ntiles = (cnt + RTILE - 1) / RTILE;

    for (int tile = blockIdx.x; tile < ntiles; tile += gridDim.x) {
        #pragma unroll
        for (int p = 0; p < RTILE; ++p) {
            int i = tile * RTILE + p;
            int real = (i < cnt);
            int n = rlist[real ? i : (cnt - 1)];
            if (t == 0) nn[p] = real ? n : -1;
            int b = n >> 10, hw = n & 1023;
            zs[p][t] = z[(size_t)b * ZSTRB + (size_t)t * HWSZ + hw];
        }
        __syncthreads();
        if (t < RTILE) s8[t] = np_sumsq256(&zs[t][0]);
        __syncthreads();

        float bestv[RTILE]; int besti[RTILE];
        #pragma unroll
        for (int p = 0; p < RTILE; ++p) { bestv[p] = 3.4e38f; besti[p] = 0; }

        #pragma unroll 1
        for (int j = 0; j < 4; ++j) {
            int k = t + 256 * j;                 // j ascending -> lowest-k tie kept
            double acc[RTILE];
            #pragma unroll
            for (int p = 0; p < RTILE; ++p) acc[p] = 0.0;
            const float* cp = cbT + k;
            #pragma unroll 2
            for (int d = 0; d < DDIM; ++d) {
                double c = (double)cp[d * KCODE];
                #pragma unroll
                for (int p = 0; p < RTILE; ++p)
                    acc[p] = fma(c, (double)zs[p][d], acc[p]);
            }
            float ek = enorm[k];
            #pragma unroll
            for (int p = 0; p < RTILE; ++p) {
                float E = (float)acc[p];
                float w = 2.0f * E;
                float u = s8[p] + ek;
                float dd = u - w;
                if (dd < bestv[p]) { bestv[p] = dd; besti[p] = k; }
            }
        }

        // per-point block reduction (lowest-index tiebreak)
        for (int p = 0; p < RTILE; ++p) {
            bv[t] = bestv[p]; bi[t] = besti[p];
            __syncthreads();
            for (int s2 = 128; s2; s2 >>= 1) {
                if (t < s2) {
                    if (bv[t + s2] < bv[t] || (bv[t + s2] == bv[t] && bi[t + s2] < bi[t])) {
                        bv[t] = bv[t + s2]; bi[t] = bi[t + s2];
                    }
                }
                __syncthreads();
            }
            if (t == 0 && nn[p] >= 0) ws_idx[nn[p]] = bi[0];
            __syncthreads();
        }
    }
}

__global__ __launch_bounds__(256) void hist_kernel(const int* __restrict__ ws_idx,
                                                   int* __restrict__ counts,
                                                   float* __restrict__ out_idx) {
    __shared__ int h[KCODE];
    int t = threadIdx.x;
    for (int i = t; i < KCODE; i += 256) h[i] = 0;
    __syncthreads();
    int n = blockIdx.x * 256 + t;
    int idx = ws_idx[n];
    out_idx[n] = (float)idx;
    atomicAdd(&h[idx], 1);
    __syncthreads();
    for (int i = t; i < KCODE; i += 256) { int c = h[i]; if (c) atomicAdd(&counts[i], c); }
}

__global__ __launch_bounds__(256) void out_kernel(const float* __restrict__ z,
                                                  const float* __restrict__ cb,
                                                  const int* __restrict__ ws_idx,
                                                  float* __restrict__ out,
                                                  double* __restrict__ lossSum,
                                                  double* __restrict__ chsum,
                                                  double* __restrict__ zsq) {
    int t = threadIdx.x;
    size_t base = (size_t)blockIdx.x * 1024;
    int c = blockIdx.x & 255;
    int b = blockIdx.x >> 8;
    int hw = t * 4;
    const float4 zv = *(const float4*)(z + base + hw);
    int4 iv = *(const int4*)(ws_idx + b * HWSZ + hw);
    float q0 = cb[(size_t)iv.x * DDIM + c];
    float q1 = cb[(size_t)iv.y * DDIM + c];
    float q2 = cb[(size_t)iv.z * DDIM + c];
    float q3 = cb[(size_t)iv.w * DDIM + c];
    float t0 = q0 - zv.x, t1 = q1 - zv.y, t2 = q2 - zv.z, t3 = q3 - zv.w;
    float4 o; o.x = zv.x + t0; o.y = zv.y + t1; o.z = zv.z + t2; o.w = zv.w + t3;
    *(float4*)(out + base + hw) = o;

    double ls  = (double)t0 * t0 + (double)t1 * t1 + (double)t2 * t2 + (double)t3 * t3;
    double zs  = (double)zv.x + (double)zv.y + (double)zv.z + (double)zv.w;
    double zq2 = (double)zv.x * zv.x + (double)zv.y * zv.y + (double)zv.z * zv.z + (double)zv.w * zv.w;

    __shared__ double r1[4], r2[4], r3[4];
    for (int o2 = 32; o2; o2 >>= 1) {
        ls  += __shfl_down(ls,  o2, 64);
        zs  += __shfl_down(zs,  o2, 64);
        zq2 += __shfl_down(zq2, o2, 64);
    }
    if ((t & 63) == 0) { int w = t >> 6; r1[w] = ls; r2[w] = zs; r3[w] = zq2; }
    __syncthreads();
    if (t == 0) {
        atomicAdd(lossSum, r1[0] + r1[1] + r1[2] + r1[3]);
        atomicAdd(&chsum[c], r2[0] + r2[1] + r2[2] + r2[3]);
        atomicAdd(zsq, r3[0] + r3[1] + r3[2] + r3[3]);
    }
}

__global__ __launch_bounds__(256) void fin_kernel(const int* __restrict__ counts,
                                                  const double* __restrict__ lossSum,
                                                  const double* __restrict__ chsum,
                                                  const double* __restrict__ esum,
                                                  const double* __restrict__ zsq,
                                                  const double* __restrict__ enormsum,
                                                  float* __restrict__ out) {
    int t = threadIdx.x;
    double ent = 0.0;
    for (int i = t; i < KCODE; i += 256) {
        float em = (float)counts[i] / 32768.0f;
        ent += (double)(em * logf(em + 1e-10f));
    }
    double pd = chsum[t] * esum[t];

    __shared__ double r1[4], r2[4];
    for (int o2 = 32; o2; o2 >>= 1) {
        ent += __shfl_down(ent, o2, 64);
        pd  += __shfl_down(pd,  o2, 64);
    }
    if ((t & 63) == 0) { int w = t >> 6; r1[w] = ent; r2[w] = pd; }
    __syncthreads();
    if (t == 0) {
        double ENT = r1[0] + r1[1] + r1[2] + r1[3];
        double PD  = r2[0] + r2[1] + r2[2] + r2[3];
        float m = (float)(*lossSum / (double)ZELEMS);
        out[OUT_LOSS] = 0.25f * m + m;
        out[OUT_PERP] = expf((float)(-ENT));
        double md = *zsq / (double)NPTS + *enormsum / (double)KCODE
                    - (2.0 / ((double)NPTS * (double)KCODE)) * PD;
        out[OUT_MD] = (float)md;
    }
}

extern "C" void kernel_launch(void* const* d_in, const int* in_sizes, int n_in,
                              void* d_out, int out_size, void* d_ws, size_t ws_size,
                              hipStream_t stream) {
    const float* z  = (const float*)d_in[0];
    const float* cb = (const float*)d_in[1];
    float* out = (float*)d_out;
    char* ws = (char*)d_ws;

    int*    ws_idx   = (int*)(ws + WS_IDX);
    int*    counts   = (int*)(ws + WS_COUNTS);
    int*    rlist    = (int*)(ws + WS_RLIST);
    int*    rcount   = (int*)(ws + WS_RCOUNT);
    double* lossSum  = (double*)(ws + WS_LOSSSUM);
    double* zsq      = (double*)(ws + WS_ZSQ);
    double* enormsum = (double*)(ws + WS_ENSUM);
    double* chsum    = (double*)(ws + WS_CHSUM);
    double* esum     = (double*)(ws + WS_ESUM);
    float*  enorm    = (float*)(ws + WS_ENORM);
    float*  cbT      = (float*)(ws + WS_CBT);
    unsigned short* cbhi = (unsigned short*)(ws + WS_CBHI);
    unsigned short* cblo = (unsigned short*)(ws + WS_CBLO);

    hipLaunchKernelGGL(init_kernel, dim3(1), dim3(256), 0, stream, ws);
    hipLaunchKernelGGL(prep2_kernel, dim3(64), dim3(256), 0, stream,
                       cb, enorm, cbT, cbhi, cblo, esum, enormsum);
    hipLaunchKernelGGL(screen_kernel, dim3(512), dim3(256), 0, stream,
                       z, cbhi, cblo, enorm, ws_idx, rlist, rcount);
    hipLaunchKernelGGL(recheck_kernel, dim3(512), dim3(256), 0, stream,
                       z, cbT, enorm, ws_idx, rlist, rcount);
    hipLaunchKernelGGL(hist_kernel, dim3(128), dim3(256), 0, stream,
                       ws_idx, counts, out + OUT_IDX);
    hipLaunchKernelGGL(out_kernel, dim3(8192), dim3(256), 0, stream,
                       z, cb, ws_idx, out, lossSum, chsum, zsq);
    hipLaunchKernelGGL(fin_kernel, dim3(1), dim3(256), 0, stream,
                       counts, lossSum, chsum, esum, zsq, enormsum, out);
}

// Round 12
// 624.146 us; speedup vs baseline: 1.2859x; 1.1713x over previous
//
#include <hip/hip_runtime.h>
#include <hip/hip_bf16.h>

// Problem: VectorQuantizer. z: [32,256,32,32] f32 NCHW, codebook: [1024,256] f32.
// Outputs (concat f32): z_q_out [32,256,32,32], loss[1], perplexity[1], idx[32768] (as float), mean_distance[1].
// idx must replicate numpy-fp32 argmin of d = fl32(fl32(s_n + t_k) - 2*fl32(dot)).
// Screen: A-side split-bf16 MFMA ((zh+zl).eh), code-split columns; batched exact-np recheck.

#define NPTS   32768
#define KCODE  1024
#define DDIM   256
#define HWSZ   1024
#define ZSTRB  262144
#define ZELEMS 8388608

#define OUT_LOSS 8388608
#define OUT_PERP 8388609
#define OUT_IDX  8388610
#define OUT_MD   8421378

// ws byte offsets
#define WS_IDX     0        // int[32768]
#define WS_COUNTS  131072   // int[1024]
#define WS_RLIST   135168   // int[32768]
#define WS_RCOUNT  266240   // int
#define WS_LOSSSUM 266248   // double
#define WS_ZSQ     266256   // double
#define WS_ENSUM   266264   // double
#define WS_CHSUM   266272   // double[256]
#define WS_ESUM    268320   // double[256]
#define WS_ENORM   270368   // float[1024]
#define WS_CBT     274464   // float[256*1024]
#define WS_CBHI    1323040  // ushort[1024*256] bf16 hi
#define WS_COLB    1847328  // float[2][32768]
#define WS_COLS    2109472  // float[2][32768]
#define WS_COLI    2371616  // int[2][32768]

// screen err ((zh+zl).eh): ~2e-5 std; np flip window 6.2e-5
#define MARGIN 3e-4f

#define RTILE 8   // points per recheck tile

typedef short  s16x8 __attribute__((ext_vector_type(8)));
typedef unsigned short u16x8 __attribute__((ext_vector_type(8)));
typedef float  f32x4 __attribute__((ext_vector_type(4)));

__device__ __forceinline__ unsigned short bf16_rne(float f) {
    unsigned int u = __float_as_uint(f);
    return (unsigned short)((u + 0x7FFFu + ((u >> 16) & 1u)) >> 16);
}

__global__ __launch_bounds__(256) void init_kernel(char* ws) {
    int t = threadIdx.x;
    int* counts = (int*)(ws + WS_COUNTS);
    for (int i = t; i < 1024; i += 256) counts[i] = 0;
    if (t == 0) *(int*)(ws + WS_RCOUNT) = 0;
    double* dbl = (double*)(ws + WS_LOSSSUM);
    for (int i = t; i < 515; i += 256) dbl[i] = 0.0;
}

// numpy pairwise fp32 sum of squares of a 256-row (exact tree; asm stops FMA contraction)
__device__ __forceinline__ float np_sumsq256(const float* p) {
    float tot[2];
    #pragma unroll
    for (int h = 0; h < 2; ++h) {
        const float* a = p + h * 128;
        float r[8];
        #pragma unroll
        for (int j = 0; j < 8; ++j) { float v = a[j]; float s = v * v; asm volatile("" : "+v"(s)); r[j] = s; }
        for (int i = 8; i < 128; i += 8) {
            #pragma unroll
            for (int j = 0; j < 8; ++j) { float v = a[i + j]; float s = v * v; asm volatile("" : "+v"(s)); r[j] += s; }
        }
        tot[h] = ((r[0] + r[1]) + (r[2] + r[3])) + ((r[4] + r[5]) + (r[6] + r[7]));
    }
    return tot[0] + tot[1];
}

// per 16 codes (64 blocks): np-fp32 enorm, cbT[d][k], cb hi bf16, fp64 column sums + norm total
__global__ __launch_bounds__(256) void prep2_kernel(const float* __restrict__ cb,
                                                    float* __restrict__ enorm,
                                                    float* __restrict__ cbT,
                                                    unsigned short* __restrict__ cbhi,
                                                    double* __restrict__ esum,
                                                    double* __restrict__ enormsum) {
    __shared__ float tile[16][257];
    int t = threadIdx.x;
    int k0 = blockIdx.x * 16;           // 64 blocks

    #pragma unroll
    for (int i = 0; i < 4; ++i) {
        int f = t + 256 * i;            // float4 index
        int r = f >> 6;
        int c4 = (f & 63) << 2;
        float4 v = *(const float4*)(cb + (size_t)(k0 + r) * DDIM + c4);
        tile[r][c4] = v.x; tile[r][c4 + 1] = v.y; tile[r][c4 + 2] = v.z; tile[r][c4 + 3] = v.w;
    }
    __syncthreads();

    if (t < 16) {
        float s = np_sumsq256(&tile[t][0]);
        enorm[k0 + t] = s;
        double en = (double)s;
        for (int o = 8; o; o >>= 1) en += __shfl_down(en, o, 64);
        if (t == 0) atomicAdd(enormsum, en);
    }

    double cs = 0.0;
    for (int r = 0; r < 16; ++r) cs += (double)tile[r][t];
    atomicAdd(&esum[t], cs);

    // cbT transposed write for recheck / out gather
    {
        int kloc = t & 15, dg = t >> 4;
        #pragma unroll
        for (int dd = 0; dd < 16; ++dd) {
            int d = dd * 16 + dg;
            cbT[(size_t)d * KCODE + k0 + kloc] = tile[kloc][d];
        }
    }

    // bf16-hi rows (row-major [k][d])
    {
        int row = t >> 4;
        int d0 = (t & 15) * 16;
        #pragma unroll
        for (int j = 0; j < 2; ++j) {
            u16x8 H;
            #pragma unroll
            for (int e = 0; e < 8; ++e) H[e] = bf16_rne(tile[row][d0 + j * 8 + e]);
            *(u16x8*)(cbhi + (size_t)(k0 + row) * DDIM + d0 + j * 8) = H;
        }
    }
}

// MFMA screen v3: grid (512 point-blocks, 2 code-columns). 64 points/block (4 waves x 16 pts),
// 512 codes/column. dot ~= (zh+zl).eh : A hi+lo in regs, B = cbhi only. 4 acc chains.
__global__ __launch_bounds__(256, 4) void screen_kernel(const float* __restrict__ z,
                                                        const unsigned short* __restrict__ cbhi,
                                                        const float* __restrict__ enorm,
                                                        float* __restrict__ colb,
                                                        float* __restrict__ colsec,
                                                        int* __restrict__ coli) {
    int tid = threadIdx.x;
    int n0 = blockIdx.x * 64;
    int kbase = blockIdx.y * 512;
    int b = n0 >> 10, hw0 = n0 & 1023;
    int lane = tid & 63;
    int w = tid >> 6;
    int colslot = lane & 15;    // A-row (point slot) and B-col (code slot)
    int kq = lane >> 4;         // K-quarter

    // A-fragments (hi + residual-lo) direct from global
    const float* zp = z + (size_t)b * ZSTRB + (hw0 + w * 16 + colslot);
    s16x8 ah[8], al[8];
    #pragma unroll
    for (int kc = 0; kc < 8; ++kc) {
        u16x8 H, L;
        #pragma unroll
        for (int e = 0; e < 8; ++e) {
            float f = zp[(size_t)(kc * 32 + kq * 8 + e) << 10];
            unsigned short h = bf16_rne(f);
            H[e] = h;
            L[e] = bf16_rne(f - __uint_as_float((unsigned int)h << 16));
        }
        union { u16x8 u; s16x8 s; } c1, c2; c1.u = H; c2.u = L;
        ah[kc] = c1.s; al[kc] = c2.s;
    }

    float best[4] = {3.4e38f, 3.4e38f, 3.4e38f, 3.4e38f};
    float sec[4]  = {3.4e38f, 3.4e38f, 3.4e38f, 3.4e38f};
    int bidx[4] = {0, 0, 0, 0};

    const char* bhbase = (const char*)cbhi + (size_t)kbase * 512 + colslot * 512 + kq * 16;

    #pragma unroll 2
    for (int chunk = 0; chunk < 32; ++chunk) {
        const char* bh = bhbase + (size_t)chunk * 8192;
        f32x4 c[4];
        #pragma unroll
        for (int q = 0; q < 4; ++q) c[q] = (f32x4){0.f, 0.f, 0.f, 0.f};
        #pragma unroll
        for (int kc = 0; kc < 8; ++kc) {
            s16x8 vbh = *(const s16x8*)(bh + kc * 64);
            c[kc & 3] = __builtin_amdgcn_mfma_f32_16x16x32_bf16(ah[kc], vbh, c[kc & 3], 0, 0, 0);
            c[kc & 3] = __builtin_amdgcn_mfma_f32_16x16x32_bf16(al[kc], vbh, c[kc & 3], 0, 0, 0);
        }
        int k = kbase + chunk * 16 + colslot;
        float ek = enorm[k];
        #pragma unroll
        for (int r = 0; r < 4; ++r) {
            float dot = (c[0][r] + c[1][r]) + (c[2][r] + c[3][r]);
            float cr = fmaf(-2.f, dot, ek);
            if (cr < best[r]) { sec[r] = best[r]; best[r] = cr; bidx[r] = k; }
            else if (cr < sec[r]) sec[r] = cr;
        }
    }

    // merge across 16 code-slots; ties -> lower idx; equal values leave sec==best -> flagged later
    #pragma unroll
    for (int m = 1; m < 16; m <<= 1) {
        #pragma unroll
        for (int r = 0; r < 4; ++r) {
            float ob = __shfl_xor(best[r], m, 64);
            float os = __shfl_xor(sec[r], m, 64);
            int   oi = __shfl_xor(bidx[r], m, 64);
            if (ob < best[r] || (ob == best[r] && oi < bidx[r])) {
                sec[r] = fminf(best[r], os);
                best[r] = ob; bidx[r] = oi;
            } else {
                sec[r] = fminf(sec[r], ob);
            }
        }
    }

    if (colslot == 0) {
        int cbase = blockIdx.y * NPTS;
        #pragma unroll
        for (int r = 0; r < 4; ++r) {
            int n = n0 + w * 16 + kq * 4 + r;   // C row = kq*4 + r
            colb[cbase + n] = best[r];
            colsec[cbase + n] = sec[r];
            coli[cbase + n] = bidx[r];
        }
    }
}

// merge 2 code-columns (ascending => lowest-index ties) + margin flag
__global__ __launch_bounds__(256) void merge_kernel(const float* __restrict__ colb,
                                                    const float* __restrict__ colsec,
                                                    const int* __restrict__ coli,
                                                    int* __restrict__ ws_idx,
                                                    int* __restrict__ rlist,
                                                    int* __restrict__ rcount) {
    int n = blockIdx.x * 256 + threadIdx.x;
    float B = colb[n], S = colsec[n];
    int I = coli[n];
    float b2 = colb[NPTS + n], s2 = colsec[NPTS + n];
    int i2 = coli[NPTS + n];
    if (b2 < B) { S = fminf(B, s2); I = i2; B = b2; }
    else        { S = fminf(S, b2); }
    ws_idx[n] = I;
    if (S - B < MARGIN) {
        int slot = atomicAdd(rcount, 1);
        if (slot < NPTS) rlist[slot] = n;
    }
}

// Batched recheck: 8 flagged points per tile; np-fp32 semantics, first-index ties.
__global__ __launch_bounds__(256) void recheck_kernel(const float* __restrict__ z,
                                                      const float* __restrict__ cbT,
                                                      const float* __restrict__ enorm,
                                                      int* __restrict__ ws_idx,
                                                      const int* __restrict__ rlist,
                                                      const int* __restrict__ rcount) {
    __shared__ float zs[RTILE][DDIM + 1];
    __shared__ float s8[RTILE];
    __shared__ int   nn[RTILE];
    __shared__ float bv[256];
    __shared__ int   bi[256];
    int t = threadIdx.x;
    int cnt = *rcount; if (cnt > NPTS) cnt = NPTS;
    int ntiles = (cnt + RTILE - 1) / RTILE;

    for (int tile = blockIdx.x; tile < ntiles; tile += gridDim.x) {
        #pragma unroll
        for (int p = 0; p < RTILE; ++p) {
            int i = tile * RTILE + p;
            int real = (i < cnt);
            int n = rlist[real ? i : (cnt - 1)];
            if (t == 0) nn[p] = real ? n : -1;
            int b = n >> 10, hw = n & 1023;
            zs[p][t] = z[(size_t)b * ZSTRB + (size_t)t * HWSZ + hw];
        }
        __syncthreads();
        if (t < RTILE) s8[t] = np_sumsq256(&zs[t][0]);
        __syncthreads();

        float bestv[RTILE]; int besti[RTILE];
        #pragma unroll
        for (int p = 0; p < RTILE; ++p) { bestv[p] = 3.4e38f; besti[p] = 0; }

        #pragma unroll 1
        for (int j = 0; j < 4; ++j) {
            int k = t + 256 * j;                 // j ascending -> lowest-k tie kept
            double acc[RTILE];
            #pragma unroll
            for (int p = 0; p < RTILE; ++p) acc[p] = 0.0;
            const float* cp = cbT + k;
            #pragma unroll 2
            for (int d = 0; d < DDIM; ++d) {
                double c = (double)cp[d * KCODE];
                #pragma unroll
                for (int p = 0; p < RTILE; ++p)
                    acc[p] = fma(c, (double)zs[p][d], acc[p]);
            }
            float ek = enorm[k];
            #pragma unroll
            for (int p = 0; p < RTILE; ++p) {
                float E = (float)acc[p];
                float w = 2.0f * E;
                float u = s8[p] + ek;
                float dd = u - w;
                if (dd < bestv[p]) { bestv[p] = dd; besti[p] = k; }
            }
        }

        for (int p = 0; p < RTILE; ++p) {
            bv[t] = bestv[p]; bi[t] = besti[p];
            __syncthreads();
            for (int s2 = 128; s2; s2 >>= 1) {
                if (t < s2) {
                    if (bv[t + s2] < bv[t] || (bv[t + s2] == bv[t] && bi[t + s2] < bi[t])) {
                        bv[t] = bv[t + s2]; bi[t] = bi[t + s2];
                    }
                }
                __syncthreads();
            }
            if (t == 0 && nn[p] >= 0) ws_idx[nn[p]] = bi[0];
            __syncthreads();
        }
    }
}

__global__ __launch_bounds__(256) void hist_kernel(const int* __restrict__ ws_idx,
                                                   int* __restrict__ counts,
                                                   float* __restrict__ out_idx) {
    __shared__ int h[KCODE];
    int t = threadIdx.x;
    for (int i = t; i < KCODE; i += 256) h[i] = 0;
    __syncthreads();
    int n = blockIdx.x * 256 + t;
    int idx = ws_idx[n];
    out_idx[n] = (float)idx;
    atomicAdd(&h[idx], 1);
    __syncthreads();
    for (int i = t; i < KCODE; i += 256) { int c = h[i]; if (c) atomicAdd(&counts[i], c); }
}

// z_q_out + loss/chsum/zsq; codebook gathered via cbT (wave's idx span one 4KB row -> few lines)
__global__ __launch_bounds__(256) void out_kernel(const float* __restrict__ z,
                                                  const float* __restrict__ cbT,
                                                  const int* __restrict__ ws_idx,
                                                  float* __restrict__ out,
                                                  double* __restrict__ lossSum,
                                                  double* __restrict__ chsum,
                                                  double* __restrict__ zsq) {
    int t = threadIdx.x;
    size_t base = (size_t)blockIdx.x * 1024;
    int c = blockIdx.x & 255;
    int b = blockIdx.x >> 8;
    int hw = t * 4;
    const float4 zv = *(const float4*)(z + base + hw);
    int4 iv = *(const int4*)(ws_idx + b * HWSZ + hw);
    const float* crow = cbT + (size_t)c * KCODE;
    float q0 = crow[iv.x];
    float q1 = crow[iv.y];
    float q2 = crow[iv.z];
    float q3 = crow[iv.w];
    float t0 = q0 - zv.x, t1 = q1 - zv.y, t2 = q2 - zv.z, t3 = q3 - zv.w;
    float4 o; o.x = zv.x + t0; o.y = zv.y + t1; o.z = zv.z + t2; o.w = zv.w + t3;
    *(float4*)(out + base + hw) = o;

    double ls  = (double)t0 * t0 + (double)t1 * t1 + (double)t2 * t2 + (double)t3 * t3;
    double zs  = (double)zv.x + (double)zv.y + (double)zv.z + (double)zv.w;
    double zq2 = (double)zv.x * zv.x + (double)zv.y * zv.y + (double)zv.z * zv.z + (double)zv.w * zv.w;

    __shared__ double r1[4], r2[4], r3[4];
    for (int o2 = 32; o2; o2 >>= 1) {
        ls  += __shfl_down(ls,  o2, 64);
        zs  += __shfl_down(zs,  o2, 64);
        zq2 += __shfl_down(zq2, o2, 64);
    }
    if ((t & 63) == 0) { int w = t >> 6; r1[w] = ls; r2[w] = zs; r3[w] = zq2; }
    __syncthreads();
    if (t == 0) {
        atomicAdd(lossSum, r1[0] + r1[1] + r1[2] + r1[3]);
        atomicAdd(&chsum[c], r2[0] + r2[1] + r2[2] + r2[3]);
        atomicAdd(zsq, r3[0] + r3[1] + r3[2] + r3[3]);
    }
}

__global__ __launch_bounds__(256) void fin_kernel(const int* __restrict__ counts,
                                                  const double* __restrict__ lossSum,
                                                  const double* __restrict__ chsum,
                                                  const double* __restrict__ esum,
                                                  const double* __restrict__ zsq,
                                                  const double* __restrict__ enormsum,
                                                  float* __restrict__ out) {
    int t = threadIdx.x;
    double ent = 0.0;
    for (int i = t; i < KCODE; i += 256) {
        float em = (float)counts[i] / 32768.0f;
        ent += (double)(em * logf(em + 1e-10f));
    }
    double pd = chsum[t] * esum[t];

    __shared__ double r1[4], r2[4];
    for (int o2 = 32; o2; o2 >>= 1) {
        ent += __shfl_down(ent, o2, 64);
        pd  += __shfl_down(pd,  o2, 64);
    }
    if ((t & 63) == 0) { int w = t >> 6; r1[w] = ent; r2[w] = pd; }
    __syncthreads();
    if (t == 0) {
        double ENT = r1[0] + r1[1] + r1[2] + r1[3];
        double PD  = r2[0] + r2[1] + r2[2] + r2[3];
        float m = (float)(*lossSum / (double)ZELEMS);
        out[OUT_LOSS] = 0.25f * m + m;
        out[OUT_PERP] = expf((float)(-ENT));
        double md = *zsq / (double)NPTS + *enormsum / (double)KCODE
                    - (2.0 / ((double)NPTS * (double)KCODE)) * PD;
        out[OUT_MD] = (float)md;
    }
}

extern "C" void kernel_launch(void* const* d_in, const int* in_sizes, int n_in,
                              void* d_out, int out_size, void* d_ws, size_t ws_size,
                              hipStream_t stream) {
    const float* z  = (const float*)d_in[0];
    const float* cb = (const float*)d_in[1];
    float* out = (float*)d_out;
    char* ws = (char*)d_ws;

    int*    ws_idx   = (int*)(ws + WS_IDX);
    int*    counts   = (int*)(ws + WS_COUNTS);
    int*    rlist    = (int*)(ws + WS_RLIST);
    int*    rcount   = (int*)(ws + WS_RCOUNT);
    double* lossSum  = (double*)(ws + WS_LOSSSUM);
    double* zsq      = (double*)(ws + WS_ZSQ);
    double* enormsum = (double*)(ws + WS_ENSUM);
    double* chsum    = (double*)(ws + WS_CHSUM);
    double* esum     = (double*)(ws + WS_ESUM);
    float*  enorm    = (float*)(ws + WS_ENORM);
    float*  cbT      = (float*)(ws + WS_CBT);
    unsigned short* cbhi = (unsigned short*)(ws + WS_CBHI);
    float*  colb     = (float*)(ws + WS_COLB);
    float*  colsec   = (float*)(ws + WS_COLS);
    int*    coli     = (int*)(ws + WS_COLI);

    hipLaunchKernelGGL(init_kernel, dim3(1), dim3(256), 0, stream, ws);
    hipLaunchKernelGGL(prep2_kernel, dim3(64), dim3(256), 0, stream,
                       cb, enorm, cbT, cbhi, esum, enormsum);
    hipLaunchKernelGGL(screen_kernel, dim3(512, 2), dim3(256), 0, stream,
                       z, cbhi, enorm, colb, colsec, coli);
    hipLaunchKernelGGL(merge_kernel, dim3(128), dim3(256), 0, stream,
                       colb, colsec, coli, ws_idx, rlist, rcount);
    hipLaunchKernelGGL(recheck_kernel, dim3(512), dim3(256), 0, stream,
                       z, cbT, enorm, ws_idx, rlist, rcount);
    hipLaunchKernelGGL(hist_kernel, dim3(128), dim3(256), 0, stream,
                       ws_idx, counts, out + OUT_IDX);
    hipLaunchKernelGGL(out_kernel, dim3(8192), dim3(256), 0, stream,
                       z, cbT, ws_idx, out, lossSum, chsum, zsq);
    hipLaunchKernelGGL(fin_kernel, dim3(1), dim3(256), 0, stream,
                       counts, lossSum, chsum, esum, zsq, enormsum, out);
}